// Round 1
// 598.362 us; speedup vs baseline: 1.0108x; 1.0108x over previous
//
#include <hip/hip_runtime.h>
#include <math.h>

// x: (B=64, C=128, T=10000) float32, contiguous, t fastest.
// Stage 1: m[b,t] = mean_c x[b,c,t]
// Stage 2: y = x - m;  per-(b,c): out = (y - mean_t y) / std_t y   (std==0 -> 1)

#define BB 64
#define CC 128
#define TT 10000
#define T4 2500   // TT/4
#define K2 10     // ceil(T4/256): float4 elements owned per thread in zscore

// ---------------------------------------------------------------------------
// Kernel 1: channel mean.  4 waves per block; each wave sums 32 of the 128
// channels for 64 consecutive float4 columns -> 2560 blocks (vs 640 before),
// 4x the in-flight loads and 1/4 the serial accumulate chain.
// ---------------------------------------------------------------------------
__global__ __launch_bounds__(256) void chmean_kernel(const float4* __restrict__ x,
                                                     float4* __restrict__ m) {
    __shared__ float4 sh[4][64];   // 4 KB

    const int tid  = threadIdx.x;
    const int wave = tid >> 6;
    const int lane = tid & 63;
    const int t4   = blockIdx.x * 64 + lane;
    const int b    = blockIdx.y;

    const float4* xb = x + (size_t)b * CC * T4;

    float4 acc = make_float4(0.f, 0.f, 0.f, 0.f);
    if (t4 < T4) {
        const int c0 = wave * 32;
#pragma unroll 8
        for (int cc = 0; cc < 32; ++cc) {
            float4 v = xb[(size_t)(c0 + cc) * T4 + t4];
            acc.x += v.x; acc.y += v.y; acc.z += v.z; acc.w += v.w;
        }
    }
    sh[wave][lane] = acc;
    __syncthreads();

    if (wave == 0 && t4 < T4) {
        float4 a0 = sh[0][lane], a1 = sh[1][lane], a2 = sh[2][lane], a3 = sh[3][lane];
        const float s = 1.0f / (float)CC;
        float4 r;
        r.x = (a0.x + a1.x + a2.x + a3.x) * s;
        r.y = (a0.y + a1.y + a2.y + a3.y) * s;
        r.z = (a0.z + a1.z + a2.z + a3.z) * s;
        r.w = (a0.w + a1.w + a2.w + a3.w) * s;
        m[(size_t)b * T4 + t4] = r;
    }
}

// ---------------------------------------------------------------------------
// Kernel 2: zscore.  Register-staged: each thread keeps its ~10 float4 of the
// row in VGPRs (fully unrolled, constant indices -> no scratch), eliminating
// the 40 KB LDS buffer (occupancy cap) and the LDS write+read round trip.
// ---------------------------------------------------------------------------
__global__ __launch_bounds__(256) void zscore_kernel(const float4* __restrict__ x,
                                                     const float4* __restrict__ m,
                                                     float4* __restrict__ out) {
    __shared__ float redS[4], redQ[4];
    __shared__ float s_mean, s_inv;

    const int tid = threadIdx.x;
    const int b = blockIdx.x >> 7;    // / 128
    const int c = blockIdx.x & 127;

    const float4* xr = x + ((size_t)b * CC + c) * T4;
    const float4* mr = m + (size_t)b * T4;

    float4 yv[K2];                    // stays in VGPRs: all indices compile-time
    float sum = 0.f, sq = 0.f;
#pragma unroll
    for (int k = 0; k < K2; ++k) {
        const int i = tid + k * 256;
        if (i < T4) {
            float4 v  = xr[i];
            float4 mv = mr[i];
            v.x -= mv.x; v.y -= mv.y; v.z -= mv.z; v.w -= mv.w;
            yv[k] = v;
            sum += v.x + v.y + v.z + v.w;
            sq  += v.x * v.x + v.y * v.y + v.z * v.z + v.w * v.w;
        }
    }

    // wave (64-lane) butterfly reduce
#pragma unroll
    for (int off = 32; off > 0; off >>= 1) {
        sum += __shfl_down(sum, off, 64);
        sq  += __shfl_down(sq,  off, 64);
    }
    const int wave = tid >> 6;
    if ((tid & 63) == 0) { redS[wave] = sum; redQ[wave] = sq; }
    __syncthreads();

    if (tid == 0) {
        const float S = redS[0] + redS[1] + redS[2] + redS[3];
        const float Q = redQ[0] + redQ[1] + redQ[2] + redQ[3];
        const float mean = S / (float)TT;
        float var = Q / (float)TT - mean * mean;
        if (var < 0.f) var = 0.f;
        const float sd = sqrtf(var);
        s_mean = mean;
        s_inv = (sd == 0.f) ? 1.f : 1.f / sd;
    }
    __syncthreads();

    const float mean = s_mean, inv = s_inv;
    float4* orow = out + ((size_t)b * CC + c) * T4;
#pragma unroll
    for (int k = 0; k < K2; ++k) {
        const int i = tid + k * 256;
        if (i < T4) {
            float4 v = yv[k];
            v.x = (v.x - mean) * inv;
            v.y = (v.y - mean) * inv;
            v.z = (v.z - mean) * inv;
            v.w = (v.w - mean) * inv;
            orow[i] = v;
        }
    }
}

extern "C" void kernel_launch(void* const* d_in, const int* in_sizes, int n_in,
                              void* d_out, int out_size, void* d_ws, size_t ws_size,
                              hipStream_t stream) {
    const float4* x = (const float4*)d_in[0];
    float4* out = (float4*)d_out;
    float4* m = (float4*)d_ws;   // 64*2500 float4 = 2.56 MB scratch

    dim3 g1((T4 + 63) / 64, BB);
    chmean_kernel<<<g1, 256, 0, stream>>>(x, m);

    zscore_kernel<<<BB * CC, 256, 0, stream>>>(x, m, out);
}

// Round 2
// 581.143 us; speedup vs baseline: 1.0408x; 1.0296x over previous
//
#include <hip/hip_runtime.h>
#include <math.h>

// x: (B=64, C=128, T=10000) float32, contiguous, t fastest.
// Stage 1: m[b,t] = mean_c x[b,c,t]
// Stage 2: y = x - m;  per-(b,c): out = (y - mean_t y) / std_t y   (std==0 -> 1)
//
// L3-locality schedule: process batches in groups of GB=16 (82 MB x-slab).
// chmean(g) pulls the slab from HBM into the 256 MB Infinity Cache; zscore(g)
// re-reads it as L3 hits. Stream order gives the stage1->stage2 dependency.

#define BB 64
#define CC 128
#define TT 10000
#define T4 2500   // TT/4
#define K2 10     // ceil(T4/256): float4 elements owned per thread in zscore
#define GB 16     // batches per group (16*5.12MB = 82 MB slab, fits L3)
#define NG 4      // number of groups (BB/GB)

// ---------------------------------------------------------------------------
// Kernel 1: channel mean over one group of GB batches.
// 4 waves per block; each wave sums 32 of the 128 channels for 64 consecutive
// float4 columns. blockIdx.y = batch-local-to-group.
// ---------------------------------------------------------------------------
__global__ __launch_bounds__(256) void chmean_kernel(const float4* __restrict__ x,
                                                     float4* __restrict__ m) {
    __shared__ float4 sh[4][64];   // 4 KB

    const int tid  = threadIdx.x;
    const int wave = tid >> 6;
    const int lane = tid & 63;
    const int t4   = blockIdx.x * 64 + lane;
    const int b    = blockIdx.y;

    const float4* xb = x + (size_t)b * CC * T4;

    float4 acc = make_float4(0.f, 0.f, 0.f, 0.f);
    if (t4 < T4) {
        const int c0 = wave * 32;
#pragma unroll 8
        for (int cc = 0; cc < 32; ++cc) {
            float4 v = xb[(size_t)(c0 + cc) * T4 + t4];
            acc.x += v.x; acc.y += v.y; acc.z += v.z; acc.w += v.w;
        }
    }
    sh[wave][lane] = acc;
    __syncthreads();

    if (wave == 0 && t4 < T4) {
        float4 a0 = sh[0][lane], a1 = sh[1][lane], a2 = sh[2][lane], a3 = sh[3][lane];
        const float s = 1.0f / (float)CC;
        float4 r;
        r.x = (a0.x + a1.x + a2.x + a3.x) * s;
        r.y = (a0.y + a1.y + a2.y + a3.y) * s;
        r.z = (a0.z + a1.z + a2.z + a3.z) * s;
        r.w = (a0.w + a1.w + a2.w + a3.w) * s;
        m[(size_t)b * T4 + t4] = r;
    }
}

// ---------------------------------------------------------------------------
// Kernel 2: zscore over one group of GB batches. Register-staged: each thread
// keeps its ~10 float4 of the row in VGPRs (fully unrolled, constant indices).
// blockIdx.x = (batch-local-to-group << 7) | channel.
// ---------------------------------------------------------------------------
__global__ __launch_bounds__(256) void zscore_kernel(const float4* __restrict__ x,
                                                     const float4* __restrict__ m,
                                                     float4* __restrict__ out) {
    __shared__ float redS[4], redQ[4];
    __shared__ float s_mean, s_inv;

    const int tid = threadIdx.x;
    const int b = blockIdx.x >> 7;    // / 128 (group-local batch)
    const int c = blockIdx.x & 127;

    const float4* xr = x + ((size_t)b * CC + c) * T4;
    const float4* mr = m + (size_t)b * T4;

    float4 yv[K2];                    // stays in VGPRs: all indices compile-time
    float sum = 0.f, sq = 0.f;
#pragma unroll
    for (int k = 0; k < K2; ++k) {
        const int i = tid + k * 256;
        if (i < T4) {
            float4 v  = xr[i];
            float4 mv = mr[i];
            v.x -= mv.x; v.y -= mv.y; v.z -= mv.z; v.w -= mv.w;
            yv[k] = v;
            sum += v.x + v.y + v.z + v.w;
            sq  += v.x * v.x + v.y * v.y + v.z * v.z + v.w * v.w;
        }
    }

    // wave (64-lane) butterfly reduce
#pragma unroll
    for (int off = 32; off > 0; off >>= 1) {
        sum += __shfl_down(sum, off, 64);
        sq  += __shfl_down(sq,  off, 64);
    }
    const int wave = tid >> 6;
    if ((tid & 63) == 0) { redS[wave] = sum; redQ[wave] = sq; }
    __syncthreads();

    if (tid == 0) {
        const float S = redS[0] + redS[1] + redS[2] + redS[3];
        const float Q = redQ[0] + redQ[1] + redQ[2] + redQ[3];
        const float mean = S / (float)TT;
        float var = Q / (float)TT - mean * mean;
        if (var < 0.f) var = 0.f;
        const float sd = sqrtf(var);
        s_mean = mean;
        s_inv = (sd == 0.f) ? 1.f : 1.f / sd;
    }
    __syncthreads();

    const float mean = s_mean, inv = s_inv;
    float4* orow = out + ((size_t)b * CC + c) * T4;
#pragma unroll
    for (int k = 0; k < K2; ++k) {
        const int i = tid + k * 256;
        if (i < T4) {
            float4 v = yv[k];
            v.x = (v.x - mean) * inv;
            v.y = (v.y - mean) * inv;
            v.z = (v.z - mean) * inv;
            v.w = (v.w - mean) * inv;
            orow[i] = v;
        }
    }
}

extern "C" void kernel_launch(void* const* d_in, const int* in_sizes, int n_in,
                              void* d_out, int out_size, void* d_ws, size_t ws_size,
                              hipStream_t stream) {
    const float4* x = (const float4*)d_in[0];
    float4* out = (float4*)d_out;
    float4* m = (float4*)d_ws;   // 64*2500 float4 = 2.56 MB scratch

    for (int g = 0; g < NG; ++g) {
        const float4* xg = x + (size_t)g * GB * CC * T4;
        float4* mg = m + (size_t)g * GB * T4;
        float4* og = out + (size_t)g * GB * CC * T4;

        dim3 g1((T4 + 63) / 64, GB);
        chmean_kernel<<<g1, 256, 0, stream>>>(xg, mg);
        zscore_kernel<<<GB * CC, 256, 0, stream>>>(xg, mg, og);
    }
}